// Round 1
// 3935.603 us; speedup vs baseline: 1.0522x; 1.0522x over previous
//
#include <hip/hip_runtime.h>
#include <cstdint>

// ---------------------------------------------------------------------------
// RNNres: emb -> LSTM(T=2048,B=64,NHID=256) -> ragged mean pool -> ResNet head
//   k0: convert emb_w / W_ih to f16, bias = b_ih + b_hh
//   k1: MFMA f16 GEMM: gate_table[v] = W_ih * emb_w[v] + bias   (50257 x 1024)
//   k2: persistent recurrence, 1 WG/batch, 512 thr.
//       v2: same-wave gate pairing (lane l<32: i,g ; lane l+32: f,o of SAME
//       element) -> f/o exchange via __shfl_xor(32), no LDS round-trip.
//       Double-buffered h -> ONE barrier per step. Weights: 100/128 half2
//       pairs per row in VGPRs (budget 256 @ 2 waves/SIMD), 28/128 in LDS
//       packed as uint4 (14 x ds_read_b128 per thread per step).
//   k3: tiny fp32 head
// ---------------------------------------------------------------------------

#define NTOKEN 50257
#define NINP 256
#define NHID 256
#define BB 64
#define TT 2048
#define NRES 10
#define NFC1 85
#define EPSV 1e-5f

typedef _Float16 f16;
typedef _Float16 f16x2 __attribute__((ext_vector_type(2)));
typedef _Float16 f16x8 __attribute__((ext_vector_type(8)));
typedef float f32x4 __attribute__((ext_vector_type(4)));

static __device__ __forceinline__ float sigm(float x) { return 1.0f / (1.0f + __expf(-x)); }
static __device__ __forceinline__ float tanh_(float x) {
  float ax = fabsf(x);
  float e = __expf(-2.0f * ax);
  float t = (1.0f - e) / (1.0f + e);
  return x < 0.0f ? -t : t;
}

static __device__ __forceinline__ float fdot2(f16x2 a, f16x2 b, float c) {
#if __has_builtin(__builtin_amdgcn_fdot2)
  return __builtin_amdgcn_fdot2(a, b, c, false);
#else
  return c + (float)a[0] * (float)b[0] + (float)a[1] * (float)b[1];
#endif
}

// ---------------------------------------------------------------- k0: convert
__global__ void k0_convert(const float* __restrict__ emb_w, const float* __restrict__ W_ih,
                           const float* __restrict__ b_ih, const float* __restrict__ b_hh,
                           f16* __restrict__ emb16, f16* __restrict__ wih16,
                           float* __restrict__ bias) {
  int64_t i = (int64_t)blockIdx.x * blockDim.x + threadIdx.x;
  if (i < (int64_t)NTOKEN * NINP) emb16[i] = (f16)emb_w[i];
  if (i < 4 * NHID * NINP) wih16[i] = (f16)W_ih[i];
  if (i < 4 * NHID) bias[i] = b_ih[i] + b_hh[i];
}

// ------------------------------------------------- k1: gate-table f16 GEMM
__global__ __launch_bounds__(256) void k1_gemm(const f16* __restrict__ emb16,
                                               const f16* __restrict__ wih16,
                                               const float* __restrict__ bias,
                                               f16* __restrict__ xgtab) {
  __shared__ __align__(16) f16 a_lds[64][40];
  __shared__ __align__(16) f16 b_lds[256][40];
  const int mt = blockIdx.x;
  const int nt0 = blockIdx.y * 256;
  const int tid = threadIdx.x;
  const int lane = tid & 63;
  const int w = tid >> 6;
  const int quad = lane >> 4;
  const int l16 = lane & 15;

  f32x4 acc[16];
#pragma unroll
  for (int i = 0; i < 16; i++) acc[i] = (f32x4){0.f, 0.f, 0.f, 0.f};

  const int ar = tid >> 2;
  int av = mt * 64 + ar;
  if (av > NTOKEN - 1) av = NTOKEN - 1;
  const int ac = (tid & 3) * 8;

  for (int kb = 0; kb < 256; kb += 32) {
    *(uint4*)&a_lds[ar][ac] = *(const uint4*)&emb16[av * 256 + kb + ac];
    {
      const uint4* bs = (const uint4*)&wih16[(nt0 + tid) * 256 + kb];
      uint4* bd = (uint4*)&b_lds[tid][0];
      bd[0] = bs[0]; bd[1] = bs[1]; bd[2] = bs[2]; bd[3] = bs[3];
    }
    __syncthreads();
    f16x8 af = *(const f16x8*)&a_lds[w * 16 + l16][quad * 8];
#pragma unroll
    for (int nt = 0; nt < 16; nt++) {
      f16x8 bf = *(const f16x8*)&b_lds[nt * 16 + l16][quad * 8];
      acc[nt] = __builtin_amdgcn_mfma_f32_16x16x32_f16(af, bf, acc[nt], 0, 0, 0);
    }
    __syncthreads();
  }
#pragma unroll
  for (int nt = 0; nt < 16; nt++) {
#pragma unroll
    for (int rg = 0; rg < 4; rg++) {
      int v = mt * 64 + w * 16 + quad * 4 + rg;
      if (v < NTOKEN) {
        int n = nt0 + nt * 16 + l16;
        xgtab[v * 1024 + n] = (f16)(acc[nt][rg] + bias[n]);
      }
    }
  }
}

// ------------------------------------------------------- k2: LSTM recurrence
// One WG per batch element, 512 thr. Same-wave pairing: wave w, lane l:
//   p = w*32 + (l&31)  (element id 0..255)
//   l < 32 : rows p (i-gate) and p+512 (g-gate)
//   l >= 32: rows p+256 (f-gate) and p+768 (o-gate)
// f,o cross to the lower half-wave via __shfl_xor(32). h double-buffered in
// LDS -> exactly one __syncthreads() per timestep.
// W_hh half2 pairs: m<RK in VGPRs, m>=RK in LDS as uint4 (2 m's x 2 rows).
#define RK 100                 // must be a multiple of 4
#define LKW ((128 - RK) / 2)   // uint4 words per thread in LDS (14)
__global__ __attribute__((amdgpu_flat_work_group_size(512, 512), amdgpu_waves_per_eu(2, 2)))
void k2_rnn(
    const int* __restrict__ input, const float* __restrict__ hx0,
    const float* __restrict__ cx0, const int* __restrict__ seq_len,
    const float* __restrict__ Whh, const f16* __restrict__ xgtab,
    float* __restrict__ feat, float* __restrict__ out_hx, float* __restrict__ out_cx) {
  __shared__ uint4 lw4[LKW * 512];                 // 114688 B
  __shared__ __align__(16) f16 hpak[2][NHID];      // 1024 B

  const int b = blockIdx.x;
  const int tid = threadIdx.x;
  const int w = tid >> 6;
  const int lane = tid & 63;
  const int half = lane >> 5;
  const int p = w * 32 + (lane & 31);          // element id 0..255
  const int r0 = half ? (p + 256) : p;         // f : i
  const int r1 = half ? (p + 768) : (p + 512); // o : g

  // ---- load + pack W_hh (fp32 -> half2), split regs/LDS
  unsigned int w0[RK], w1[RK];
  unsigned int pa0 = 0, pd0 = 0;
#pragma unroll
  for (int m = 0; m < 128; m++) {
    float2 a = *(const float2*)&Whh[r0 * 256 + 2 * m];
    float2 d = *(const float2*)&Whh[r1 * 256 + 2 * m];
    f16x2 pa; pa[0] = (f16)a.x; pa[1] = (f16)a.y;
    f16x2 pd; pd[0] = (f16)d.x; pd[1] = (f16)d.y;
    unsigned int ua = __builtin_bit_cast(unsigned int, pa);
    unsigned int ud = __builtin_bit_cast(unsigned int, pd);
    if (m < RK) {
      w0[m] = ua; w1[m] = ud;
    } else if (((m - RK) & 1) == 0) {
      pa0 = ua; pd0 = ud;
    } else {
      lw4[((m - RK) >> 1) * 512 + tid] = make_uint4(pa0, pd0, ua, ud);
    }
  }

  float c = 0.0f, pool = 0.0f, hnew = 0.0f;
  if (tid < NHID) hpak[0][tid] = (f16)hx0[b * NHID + tid];
  if (!half) c = cx0[b * NHID + p];
  const int L = seq_len[b];
  __syncthreads();

  const int* tokp = input + b * TT;
  int tok_next = tokp[1];
  f16 xga, xgb;
  {
    int tok0 = tokp[0];
    xga = xgtab[tok0 * 1024 + r0];
    xgb = xgtab[tok0 * 1024 + r1];
  }

  for (int t = 0; t < TT; t++) {
    const int cur = t & 1;
    int tn = (t + 2 < TT) ? tokp[t + 2] : 0;
    f16 pfa = xgtab[tok_next * 1024 + r0];
    f16 pfb = xgtab[tok_next * 1024 + r1];

    float acc0 = (float)xga, acc1 = (float)xgb;
    const uint4* hp = (const uint4*)hpak[cur];
    uint4 hC = hp[0];
    uint4 hN = hp[1];
#pragma unroll
    for (int mb = 0; mb < 32; mb++) {
      uint4 h4 = hC;             // ds_read_b128, same address across wave -> broadcast
      hC = hN;
      if (mb < 30) hN = hp[mb + 2];
      uint4 ww0, ww1;
      if (4 * mb >= RK) {        // LDS-resident weight pairs, b128 lane-strided
        ww0 = lw4[(2 * (mb - RK / 4)) * 512 + tid];
        ww1 = lw4[(2 * (mb - RK / 4) + 1) * 512 + tid];
      }
#pragma unroll
      for (int j = 0; j < 4; j++) {
        const int m = mb * 4 + j;
        unsigned int hu = (j == 0) ? h4.x : (j == 1) ? h4.y : (j == 2) ? h4.z : h4.w;
        f16x2 hh = __builtin_bit_cast(f16x2, hu);
        f16x2 wa, wb;
        if (m < RK) {
          wa = __builtin_bit_cast(f16x2, w0[m]);
          wb = __builtin_bit_cast(f16x2, w1[m]);
        } else {
          unsigned int uwa = (j == 0) ? ww0.x : (j == 1) ? ww0.z : (j == 2) ? ww1.x : ww1.z;
          unsigned int uwb = (j == 0) ? ww0.y : (j == 1) ? ww0.w : (j == 2) ? ww1.y : ww1.w;
          wa = __builtin_bit_cast(f16x2, uwa);
          wb = __builtin_bit_cast(f16x2, uwb);
        }
        acc0 = fdot2(wa, hh, acc0);
        acc1 = fdot2(wb, hh, acc1);
      }
    }

    // s0 = sigm(i) on lower half-lanes, sigm(f) on upper half-lanes
    float s0 = sigm(acc0);
    float oa = 0.0f;
    if (half) oa = sigm(acc1);                 // sigm(o), upper only
    float fs = __shfl_xor(half ? s0 : 0.0f, 32);  // lower receives sigm(f)
    float os = __shfl_xor(oa, 32);                // lower receives sigm(o)
    if (!half) {
      float gg = tanh_(acc1);
      c = fs * c + s0 * gg;
      hnew = os * tanh_(c);
      if (t < L) pool += hnew;
      hpak[cur ^ 1][p] = (f16)hnew;
    }
    __syncthreads();
    xga = pfa; xgb = pfb; tok_next = tn;
  }

  if (!half) {
    feat[b * NHID + p] = pool / (float)L;
    out_hx[b * NHID + p] = hnew;
    out_cx[b * NHID + p] = c;
  }
}

// ------------------------------------------------------------- k3: head (fp32)
__global__ __launch_bounds__(256) void k3_head(const float* __restrict__ feat,
    const float* __restrict__ rfc1_w, const float* __restrict__ rfc1_b,
    const float* __restrict__ rbn_g, const float* __restrict__ rbn_b,
    const float* __restrict__ rbn_rm, const float* __restrict__ rbn_rv,
    const float* __restrict__ rfc2_w, const float* __restrict__ rfc2_b,
    const float* __restrict__ fc1_w, const float* __restrict__ fc1_b,
    const float* __restrict__ bn1_g, const float* __restrict__ bn1_b,
    const float* __restrict__ bn1_rm, const float* __restrict__ bn1_rv,
    const float* __restrict__ fc2_w, const float* __restrict__ fc2_b,
    float* __restrict__ logp) {
  __shared__ float f[256];
  __shared__ float f2[256];
  __shared__ float res[16];
  __shared__ float fcv[96];
  const int b = blockIdx.x, tid = threadIdx.x;
  const int wv = tid >> 6, lane = tid & 63;
  f[tid] = feat[b * 256 + tid];
  __syncthreads();
  for (int r = wv; r < NRES; r += 4) {
    float p = 0.f;
#pragma unroll
    for (int j0 = 0; j0 < 4; j0++) {
      int j = lane * 4 + j0;
      p += fmaxf(f[j], 0.f) * rfc1_w[r * 256 + j];
    }
    for (int off = 32; off > 0; off >>= 1) p += __shfl_down(p, off);
    if (lane == 0) {
      float x = p + rfc1_b[r];
      x = fmaxf(x, 0.f);
      x = (x - rbn_rm[r]) * rsqrtf(rbn_rv[r] + EPSV) * rbn_g[r] + rbn_b[r];
      res[r] = x;
    }
  }
  __syncthreads();
  {
    float s = rfc2_b[tid];
#pragma unroll
    for (int r = 0; r < NRES; r++) s += res[r] * rfc2_w[tid * NRES + r];
    f2[tid] = f[tid] + s;
  }
  __syncthreads();
  for (int o = wv; o < NFC1; o += 4) {
    float p = 0.f;
#pragma unroll
    for (int j0 = 0; j0 < 4; j0++) {
      int j = lane * 4 + j0;
      p += f2[j] * fc1_w[o * 256 + j];
    }
    for (int off = 32; off > 0; off >>= 1) p += __shfl_down(p, off);
    if (lane == 0) {
      float x = p + fc1_b[o];
      x = (x - bn1_rm[o]) * rsqrtf(bn1_rv[o] + EPSV) * bn1_g[o] + bn1_b[o];
      x = fmaxf(x, 0.01f * x);
      fcv[o] = x;
    }
  }
  __syncthreads();
  if (tid == 0) {
    float l0 = fc2_b[0], l1 = fc2_b[1];
    for (int o2 = 0; o2 < NFC1; o2++) {
      l0 += fcv[o2] * fc2_w[o2];
      l1 += fcv[o2] * fc2_w[NFC1 + o2];
    }
    float mx = fmaxf(l0, l1);
    float lse = mx + __logf(__expf(l0 - mx) + __expf(l1 - mx));
    logp[b * 2 + 0] = l0 - lse;
    logp[b * 2 + 1] = l1 - lse;
  }
}

// ---------------------------------------------------------------------------
extern "C" void kernel_launch(void* const* d_in, const int* in_sizes, int n_in,
                              void* d_out, int out_size, void* d_ws, size_t ws_size,
                              hipStream_t stream) {
  const int*   input  = (const int*)  d_in[0];
  const float* hx     = (const float*)d_in[1];
  const float* cx     = (const float*)d_in[2];
  const int*   seqlen = (const int*)  d_in[3];
  const float* emb_w  = (const float*)d_in[4];
  const float* W_ih   = (const float*)d_in[5];
  const float* W_hh   = (const float*)d_in[6];
  const float* b_ih   = (const float*)d_in[7];
  const float* b_hh   = (const float*)d_in[8];
  const float* rfc1_w = (const float*)d_in[9];
  const float* rfc1_b = (const float*)d_in[10];
  const float* rbn_g  = (const float*)d_in[11];
  const float* rbn_b  = (const float*)d_in[12];
  const float* rbn_rm = (const float*)d_in[13];
  const float* rbn_rv = (const float*)d_in[14];
  const float* rfc2_w = (const float*)d_in[15];
  const float* rfc2_b = (const float*)d_in[16];
  const float* fc1_w  = (const float*)d_in[17];
  const float* fc1_b  = (const float*)d_in[18];
  const float* bn1_g  = (const float*)d_in[19];
  const float* bn1_b  = (const float*)d_in[20];
  const float* bn1_rm = (const float*)d_in[21];
  const float* bn1_rv = (const float*)d_in[22];
  const float* fc2_w  = (const float*)d_in[23];
  const float* fc2_b  = (const float*)d_in[24];

  char* ws = (char*)d_ws;
  f16*   emb16 = (f16*)(ws);                 // 25,731,584 B
  f16*   wih16 = (f16*)(ws + 25731584);      //    524,288 B
  float* bias  = (float*)(ws + 26255872);    //      4,096 B
  f16*   xgtab = (f16*)(ws + 26259968);      // 102,926,336 B
  float* feat  = (float*)(ws + 129186304);   //     65,536 B

  float* out = (float*)d_out;   // [0,128): logp, [128,16512): hx_f, [16512,32896): cx_f

  k0_convert<<<dim3(NTOKEN), 256, 0, stream>>>(emb_w, W_ih, b_ih, b_hh, emb16, wih16, bias);
  k1_gemm<<<dim3((NTOKEN + 63) / 64, 4), 256, 0, stream>>>(emb16, wih16, bias, xgtab);
  k2_rnn<<<dim3(BB), 512, 0, stream>>>(input, hx, cx, seqlen, W_hh, xgtab, feat,
                                       out + 128, out + 128 + BB * NHID);
  k3_head<<<dim3(BB), 256, 0, stream>>>(feat, rfc1_w, rfc1_b, rbn_g, rbn_b, rbn_rm, rbn_rv,
                                        rfc2_w, rfc2_b, fc1_w, fc1_b, bn1_g, bn1_b, bn1_rm,
                                        bn1_rv, fc2_w, fc2_b, out);
}